// Round 13
// baseline (326.043 us; speedup 1.0000x reference)
//
#include <hip/hip_runtime.h>

// ImplicitNet fused MLP — R13: R10's wave body at 128 pts/block (8 waves).
// Halves the L2 weight stream (the ~4600 cyc/CU-layer pipe, == MFMA cost):
// one 512-thread block per CU reads each layer's 128 KB of weights ONCE for
// 128 points. Waves: wr = point-half (0/1), wc = feat-quarter (0..3); the two
// halves are data-independent and share only the weight stream (L1/L2 reuse).
// Single in-place 128x256 bf16 LDS buffer (64 KB static, proven size).
// Residency: ~180 unified regs/wave -> 2 waves/SIMD -> 1 block/CU (no LDS trick
// needed); launch_bounds(512,2) caps alloc at 256 = R10's proven no-spill cap.
// Kept from R10: a+b double-buffer, lgkm-only barriers, bias-in-C-init,
// in-place epilogue, packed softplus, W4 1/sqrt2 fold, cross-layer prefetch.
//
// d_ws: bf16 weights, fragment-major 16x16x32: chunk(ntile,ktile,lane) holds
// W[ntile*16+(lane&15)][ktile*32+(lane>>4)*8+j]. Padding: L0 K 51->64,
// L3 N 253->256, L8 N 257->272. ws >= 1,089,536 B.

typedef __attribute__((ext_vector_type(8))) short bf16x8;
typedef __attribute__((ext_vector_type(4))) float f32x4;
typedef __attribute__((ext_vector_type(2))) float f32x2;

#define PPTS 50000
#define NPTS 200000

__device__ __forceinline__ short f2bf(float f) {
    union { float f; unsigned u; } v; v.f = f;
    unsigned r = v.u + 0x7fffu + ((v.u >> 16) & 1u);   // RTNE (finite inputs)
    return (short)(r >> 16);
}

__device__ __forceinline__ unsigned cvt_pk_bf16(float lo, float hi) {
    unsigned r;
    asm("v_cvt_pk_bf16_f32 %0, %1, %2" : "=v"(r) : "v"(lo), "v"(hi));
    return r;
}

// lgkm-only barrier: LDS ordering without draining the global (weight) queue.
__device__ __forceinline__ void bar_lgkm() {
    asm volatile("s_waitcnt lgkmcnt(0)" ::: "memory");
    __builtin_amdgcn_s_barrier();
    __builtin_amdgcn_sched_barrier(0);
}

// softplus(100x)/100 = max(x,0) + e*(A+Be+Ce^2), e=exp(-100|x|); |err|<=2.5e-5
__device__ __forceinline__ f32x2 sp100_pair(f32x2 y) {
    const f32x2 A2 = {6.9314718e-3f, 6.9314718e-3f};
    const f32x2 B2 = {-3.11522e-3f, -3.11522e-3f};
    const f32x2 C2 = {9.8829e-4f,  9.8829e-4f};
    const f32x2 K2 = {-144.26950408889634f, -144.26950408889634f};
    const f32x2 Z2 = {0.0f, 0.0f};
    f32x2 m = __builtin_elementwise_abs(y) * K2;
    f32x2 e = {__builtin_amdgcn_exp2f(m.x), __builtin_amdgcn_exp2f(m.y)};
    f32x2 t = __builtin_elementwise_fma(C2, e, B2);
    t = __builtin_elementwise_fma(t, e, A2);
    return __builtin_elementwise_fma(e, t, __builtin_elementwise_max(y, Z2));
}
__device__ __forceinline__ void sp100_4(f32x4& v) {
    f32x2 y0 = {v[0], v[1]}, y1 = {v[2], v[3]};
    f32x2 r0 = sp100_pair(y0), r1 = sp100_pair(y1);
    v[0] = r0.x; v[1] = r0.y; v[2] = r1.x; v[3] = r1.y;
}

// LDS tile [128 rows][256 cols] bf16, row stride 512B.
// byte ^= ((row&7) ^ 5*bit3(row)) << 4 — bijective, keeps 8/16B alignment.
__device__ __forceinline__ int xswz(int row) {
    return (((row & 7) ^ (5 * ((row >> 3) & 1))) << 4);
}
__device__ __forceinline__ short* xaddr(short* base, int row, int col) {
    int off = ((row << 9) + (col << 1)) ^ xswz(row);
    return (short*)((char*)base + off);
}
__device__ __forceinline__ const short* xaddrc(const short* base, int row, int col) {
    int off = ((row << 9) + (col << 1)) ^ xswz(row);
    return (const short*)((const char*)base + off);
}

// ---------------- weight prep: f32 row-major -> bf16 fragment-major (R7 verbatim) --
__global__ void prep_kernel(
    const float* __restrict__ W0, const float* __restrict__ W1, const float* __restrict__ W2,
    const float* __restrict__ W3, const float* __restrict__ W4, const float* __restrict__ W5,
    const float* __restrict__ W6, const float* __restrict__ W7, const float* __restrict__ W8,
    short* __restrict__ wbf)
{
    const int gid = blockIdx.x * blockDim.x + threadIdx.x;
    if (gid >= 68096) return;                       // total 16B chunks
    int l, cid; const float* Wsrc;
    if      (gid <  2048) { l = 0; cid = gid;         Wsrc = W0; }
    else if (gid < 10240) { l = 1; cid = gid -  2048; Wsrc = W1; }
    else if (gid < 18432) { l = 2; cid = gid - 10240; Wsrc = W2; }
    else if (gid < 26624) { l = 3; cid = gid - 18432; Wsrc = W3; }
    else if (gid < 34816) { l = 4; cid = gid - 26624; Wsrc = W4; }
    else if (gid < 43008) { l = 5; cid = gid - 34816; Wsrc = W5; }
    else if (gid < 51200) { l = 6; cid = gid - 43008; Wsrc = W6; }
    else if (gid < 59392) { l = 7; cid = gid - 51200; Wsrc = W7; }
    else                  { l = 8; cid = gid - 59392; Wsrc = W8; }
    const int NR   = (l == 3) ? 253 : ((l == 8) ? 257 : 256);
    const int KR   = (l == 0) ? 51 : 256;
    const int klog = (l == 0) ? 1 : 3;              // ktiles = Kpad/32 = 2 or 8
    const float sc = (l == 4) ? 0.70710678f : 1.0f; // fold skip 1/sqrt2 into W4
    const int lane  = cid & 63;
    const int tile  = cid >> 6;
    const int ntile = tile >> klog;
    const int ktile = tile & ((1 << klog) - 1);
    const int n  = ntile * 16 + (lane & 15);
    const int k0 = ktile * 32 + ((lane >> 4) << 3);
    bf16x8 v;
#pragma unroll
    for (int j = 0; j < 8; ++j) {
        int k = k0 + j;
        float f = (n < NR && k < KR) ? Wsrc[n * KR + k] * sc : 0.0f;
        v[j] = f2bf(f);
    }
    ((bf16x8*)wbf)[gid] = v;
}

// ------- one hidden layer, IN PLACE, a & b double-buffered (R10 body) -------------
// Wave (wr,wc): rows [rowb, rowb+64), feats [wc*64, wc*64+64).
// ap in: ks=0 A-frags of THIS layer. ap out: ks=0 frags of NEXT layer.
// MODE 0: normal. MODE 1: layer 3 (N=253: masked col block 252).
template<int KSTEPS, int MODE>
__device__ __forceinline__ void layer_fwd(short* xb,
    const bf16x8* __restrict__ wl, const bf16x8* __restrict__ wlnext,
    const float* __restrict__ bias, int lane, int wc, int rowb, bf16x8 (&ap)[4])
{
    const int prow = lane & 15;
    const int kg   = (lane >> 4) << 3;
    const int rb4  = (lane >> 4) << 2;
    f32x4 acc[4][4];
#pragma unroll
    for (int nii = 0; nii < 4; ++nii) {
        const int cb = (wc * 4 + nii) * 16 + rb4;
        f32x4 bv;
        if (MODE == 1 && cb == 252) { f32x4 tb = {bias[252], 0.f, 0.f, 0.f}; bv = tb; }
        else bv = *(const f32x4*)(bias + cb);
#pragma unroll
        for (int mi = 0; mi < 4; ++mi)
            acc[mi][nii] = bv;
    }
    bf16x8 a_cur[4], b_cur[4];
#pragma unroll
    for (int nii = 0; nii < 4; ++nii) a_cur[nii] = ap[nii];
#pragma unroll
    for (int mi = 0; mi < 4; ++mi)
        b_cur[mi] = *(const bf16x8*)xaddrc(xb, rowb + mi * 16 + prow, kg);
#pragma unroll
    for (int ks = 0; ks < KSTEPS; ++ks) {
        bf16x8 a_nxt[4], b_nxt[4];
        if (ks + 1 < KSTEPS) {
#pragma unroll
            for (int nii = 0; nii < 4; ++nii)
                a_nxt[nii] = wl[((wc * 4 + nii) * KSTEPS + ks + 1) * 64 + lane];
#pragma unroll
            for (int mi = 0; mi < 4; ++mi)
                b_nxt[mi] = *(const bf16x8*)xaddrc(xb, rowb + mi * 16 + prow,
                                                   (ks + 1) * 32 + kg);
        } else {
#pragma unroll
            for (int nii = 0; nii < 4; ++nii)
                a_nxt[nii] = wlnext[(wc * 4 + nii) * 512 + lane];  // next layer ks=0
        }
        __builtin_amdgcn_s_setprio(1);
#pragma unroll
        for (int mi = 0; mi < 4; ++mi)
#pragma unroll
            for (int nii = 0; nii < 4; ++nii)
                acc[mi][nii] = __builtin_amdgcn_mfma_f32_16x16x32_bf16(
                    a_cur[nii], b_cur[mi], acc[mi][nii], 0, 0, 0);
        __builtin_amdgcn_s_setprio(0);
#pragma unroll
        for (int nii = 0; nii < 4; ++nii) a_cur[nii] = a_nxt[nii];
        if (ks + 1 < KSTEPS) {
#pragma unroll
            for (int mi = 0; mi < 4; ++mi) b_cur[mi] = b_nxt[mi];
        }
    }
#pragma unroll
    for (int nii = 0; nii < 4; ++nii) ap[nii] = a_cur[nii];
    // softplus in place on acc (registers only)
#pragma unroll
    for (int nii = 0; nii < 4; ++nii)
#pragma unroll
        for (int mi = 0; mi < 4; ++mi)
            sp100_4(acc[mi][nii]);
    bar_lgkm();                                       // all reads of xb complete
#pragma unroll
    for (int nii = 0; nii < 4; ++nii) {
        const int cb = (wc * 4 + nii) * 16 + rb4;
#pragma unroll
        for (int mi = 0; mi < 4; ++mi) {
            unsigned p01 = cvt_pk_bf16(acc[mi][nii][0], acc[mi][nii][1]);
            unsigned p23 = cvt_pk_bf16(acc[mi][nii][2], acc[mi][nii][3]);
            if (MODE == 1 && cb == 252) {
                *xaddr(xb, rowb + mi * 16 + prow, 252) = (short)(p01 & 0xffff);
            } else {
                uint2 pk; pk.x = p01; pk.y = p23;
                *(uint2*)xaddr(xb, rowb + mi * 16 + prow, cb) = pk;
            }
        }
    }
}

// ---------------- fused network kernel: 128 points, 8 waves, 64 KB LDS -------------
__global__ __launch_bounds__(512, 2) void net_kernel(
    const float* __restrict__ xin, const float* __restrict__ cond,
    const bf16x8* __restrict__ W,
    const float* __restrict__ b0, const float* __restrict__ b1, const float* __restrict__ b2,
    const float* __restrict__ b3, const float* __restrict__ b4, const float* __restrict__ b5,
    const float* __restrict__ b6, const float* __restrict__ b7, const float* __restrict__ b8,
    float* __restrict__ out)
{
    __shared__ short xb[128 * 256];
    const int t    = threadIdx.x;
    const int pt0  = blockIdx.x * 128;
    const int lane = t & 63;
    const int wid  = t >> 6;      // 0..7
    const int wr   = wid >> 2;    // point half
    const int wc   = wid & 3;     // feat quarter
    const int rowb = wr * 64;

    // prefetch L0 ks=0 A-frags first (hides cold weight fetch under X0 build)
    bf16x8 ap[4];
#pragma unroll
    for (int nii = 0; nii < 4; ++nii)
        ap[nii] = W[(wc * 4 + nii) * 128 + lane];   // KSTEPS(L0)=2

    // hoist skip values (written after layer 3; 1/sqrt2 folded into W4)
    float sk[3] = {0.f, 0.f, 0.f};
    if (t < 128) {
        const int p = min(pt0 + t, NPTS - 1);
#pragma unroll
        for (int c = 0; c < 3; ++c)
            sk[c] = xin[p * 3 + c];
    }

    // build X0 = [x(3) | cond(48) | zeros(..63)], bf16 into LDS cols 0..63
    {
        const int row   = t >> 2;           // 0..127
        const int c0    = (t & 3) << 4;     // 0,16,32,48
        const int point = min(pt0 + row, NPTS - 1);
        const int batch = point / PPTS;
        const float* xp = xin + point * 3;
        const float* cp = cond + batch * 48;
#pragma unroll
        for (int h = 0; h < 2; ++h) {
            bf16x8 v;
#pragma unroll
            for (int i = 0; i < 8; ++i) {
                int c = c0 + h * 8 + i;
                float f = (c < 3) ? xp[c] : ((c < 51) ? cp[c - 3] : 0.0f);
                v[i] = f2bf(f);
            }
            *(bf16x8*)xaddr(xb, row, c0 + h * 8) = v;
        }
    }
    bar_lgkm();

    layer_fwd<2, 0>(xb, W +     0, W +  2048, b0, lane, wc, rowb, ap); bar_lgkm();
    layer_fwd<8, 0>(xb, W +  2048, W + 10240, b1, lane, wc, rowb, ap); bar_lgkm();
    layer_fwd<8, 0>(xb, W + 10240, W + 18432, b2, lane, wc, rowb, ap); bar_lgkm();
    layer_fwd<8, 1>(xb, W + 18432, W + 26624, b3, lane, wc, rowb, ap);
    if (t < 128) {      // skip-concat cols 253..255 (same write window as L3)
#pragma unroll
        for (int c = 0; c < 3; ++c)
            *xaddr(xb, t, 253 + c) = f2bf(sk[c]);
    }
    bar_lgkm();
    layer_fwd<8, 0>(xb, W + 26624, W + 34816, b4, lane, wc, rowb, ap); bar_lgkm();
    layer_fwd<8, 0>(xb, W + 34816, W + 43008, b5, lane, wc, rowb, ap); bar_lgkm();
    layer_fwd<8, 0>(xb, W + 43008, W + 51200, b6, lane, wc, rowb, ap); bar_lgkm();
    layer_fwd<8, 0>(xb, W + 51200, W + 59392, b7, lane, wc, rowb, ap); bar_lgkm();

    // layer 8: N=257 (17 n-tiles), no activation, bias in acc-init, f32 store.
    // Two m-halves of the wave's 64 rows; ap feeds half 0 ks 0; a double-buffered.
    {
        const bf16x8* wl = W + 59392;
        const int prow = lane & 15;
        const int kg   = (lane >> 4) << 3;
        const int rb4  = (lane >> 4) << 2;
        const float blast = b8[256];
#pragma unroll
        for (int half = 0; half < 2; ++half) {
            f32x4 acc[2][4];
            f32x4 acc2[2];
#pragma unroll
            for (int nii = 0; nii < 4; ++nii) {
                const int cb = (wc * 4 + nii) * 16 + rb4;          // <= 252
                const f32x4 bv = *(const f32x4*)(b8 + cb);
#pragma unroll
                for (int m2 = 0; m2 < 2; ++m2)
                    acc[m2][nii] = bv;
            }
            {
                f32x4 bz = {(rb4 == 0) ? blast : 0.f, 0.f, 0.f, 0.f};
                acc2[0] = bz; acc2[1] = bz;
            }
            bf16x8 a_cur[4];
#pragma unroll
            for (int nii = 0; nii < 4; ++nii)
                a_cur[nii] = (half == 0) ? ap[nii]
                           : wl[((wc * 4 + nii) * 8) * 64 + lane];
#pragma unroll
            for (int ks = 0; ks < 8; ++ks) {
                bf16x8 a_nxt[4], a2;
                if (ks < 7) {
#pragma unroll
                    for (int nii = 0; nii < 4; ++nii)
                        a_nxt[nii] = wl[((wc * 4 + nii) * 8 + ks + 1) * 64 + lane];
                }
                if (wc == 0) a2 = wl[(128 + ks) * 64 + lane];
                bf16x8 b[2];
#pragma unroll
                for (int m2 = 0; m2 < 2; ++m2)
                    b[m2] = *(const bf16x8*)xaddrc(xb, rowb + (half * 2 + m2) * 16 + prow,
                                                   ks * 32 + kg);
                __builtin_amdgcn_s_setprio(1);
#pragma unroll
                for (int m2 = 0; m2 < 2; ++m2)
#pragma unroll
                    for (int nii = 0; nii < 4; ++nii)
                        acc[m2][nii] = __builtin_amdgcn_mfma_f32_16x16x32_bf16(
                            a_cur[nii], b[m2], acc[m2][nii], 0, 0, 0);
                if (wc == 0) {
#pragma unroll
                    for (int m2 = 0; m2 < 2; ++m2)
                        acc2[m2] = __builtin_amdgcn_mfma_f32_16x16x32_bf16(
                            a2, b[m2], acc2[m2], 0, 0, 0);
                }
                __builtin_amdgcn_s_setprio(0);
                if (ks < 7) {
#pragma unroll
                    for (int nii = 0; nii < 4; ++nii) a_cur[nii] = a_nxt[nii];
                }
            }
#pragma unroll
            for (int nii = 0; nii < 4; ++nii) {
                const int cb = (wc * 4 + nii) * 16 + rb4;          // <= 252
#pragma unroll
                for (int m2 = 0; m2 < 2; ++m2) {
                    const int pt = pt0 + rowb + (half * 2 + m2) * 16 + prow;
                    if (pt < NPTS) {
                        const int rowoff = pt * 257 + cb;
#pragma unroll
                        for (int r = 0; r < 4; ++r)
                            out[rowoff + r] = acc[m2][nii][r];
                    }
                }
            }
            if (wc == 0 && rb4 == 0) {                              // lanes 0..15
#pragma unroll
                for (int m2 = 0; m2 < 2; ++m2) {
                    const int pt = pt0 + rowb + (half * 2 + m2) * 16 + prow;
                    if (pt < NPTS) out[pt * 257 + 256] = acc2[m2][0];
                }
            }
        }
    }
}

extern "C" void kernel_launch(void* const* d_in, const int* in_sizes, int n_in,
                              void* d_out, int out_size, void* d_ws, size_t ws_size,
                              hipStream_t stream)
{
    const float* xin  = (const float*)d_in[0];
    const float* cond = (const float*)d_in[1];
    const float* Wp[9]; const float* bp[9];
    for (int l = 0; l < 9; ++l) { Wp[l] = (const float*)d_in[2 + 2 * l]; bp[l] = (const float*)d_in[3 + 2 * l]; }
    short* wbf = (short*)d_ws;   // needs 1,089,536 B

    prep_kernel<<<dim3(266), dim3(256), 0, stream>>>(
        Wp[0], Wp[1], Wp[2], Wp[3], Wp[4], Wp[5], Wp[6], Wp[7], Wp[8], wbf);
    net_kernel<<<dim3(1563), dim3(512), 0, stream>>>(
        xin, cond, (const bf16x8*)wbf,
        bp[0], bp[1], bp[2], bp[3], bp[4], bp[5], bp[6], bp[7], bp[8],
        (float*)d_out);
}

// Round 14
// 279.257 us; speedup vs baseline: 1.1675x; 1.1675x over previous
//
#include <hip/hip_runtime.h>

// ImplicitNet fused MLP — R14: R10's exact 16x16 body + PING-PONG LDS
// (1 barrier/layer, 18->9) + bias prefetched one layer ahead.
// 256 threads (4 waves), 64 pts/block, wave owns 64 feats; two 32KB buffers.
// Epilogue writes go to dst right after softplus (no pre-write barrier, writes
// overlap other waves' compute); single bar_lgkm per layer boundary.
// Bias of layer l+1 loaded during layer l (rides lgkm barriers like ap) --
// kills the ~200cyc L2 stall at each layer head (acc init = MFMA C-in).
// launch_bounds(256,2): ~196 unified regs, no spill (R10-proven budget).
//
// d_ws: bf16 weights, fragment-major 16x16x32: chunk(ntile,ktile,lane) holds
// W[ntile*16+(lane&15)][ktile*32+(lane>>4)*8+j]. Padding: L0 K 51->64,
// L3 N 253->256, L8 N 257->272. W4 pre-scaled by 1/sqrt2. ws >= 1,089,536 B.

typedef __attribute__((ext_vector_type(8))) short bf16x8;
typedef __attribute__((ext_vector_type(4))) float f32x4;
typedef __attribute__((ext_vector_type(2))) float f32x2;

#define PPTS 50000

__device__ __forceinline__ short f2bf(float f) {
    union { float f; unsigned u; } v; v.f = f;
    unsigned r = v.u + 0x7fffu + ((v.u >> 16) & 1u);   // RTNE (finite inputs)
    return (short)(r >> 16);
}

__device__ __forceinline__ unsigned cvt_pk_bf16(float lo, float hi) {
    unsigned r;
    asm("v_cvt_pk_bf16_f32 %0, %1, %2" : "=v"(r) : "v"(lo), "v"(hi));
    return r;
}

// lgkm-only barrier: LDS ordering without draining the global (weight/bias
// prefetch) queue. sched_barrier pins compiler motion (rule #18).
__device__ __forceinline__ void bar_lgkm() {
    asm volatile("s_waitcnt lgkmcnt(0)" ::: "memory");
    __builtin_amdgcn_s_barrier();
    __builtin_amdgcn_sched_barrier(0);
}

// softplus(100x)/100 = max(x,0) + e*(A+Be+Ce^2), e=exp(-100|x|); |err|<=2.5e-5
__device__ __forceinline__ f32x2 sp100_pair(f32x2 y) {
    const f32x2 A2 = {6.9314718e-3f, 6.9314718e-3f};
    const f32x2 B2 = {-3.11522e-3f, -3.11522e-3f};
    const f32x2 C2 = {9.8829e-4f,  9.8829e-4f};
    const f32x2 K2 = {-144.26950408889634f, -144.26950408889634f};
    const f32x2 Z2 = {0.0f, 0.0f};
    f32x2 m = __builtin_elementwise_abs(y) * K2;
    f32x2 e = {__builtin_amdgcn_exp2f(m.x), __builtin_amdgcn_exp2f(m.y)};
    f32x2 t = __builtin_elementwise_fma(C2, e, B2);
    t = __builtin_elementwise_fma(t, e, A2);
    return __builtin_elementwise_fma(e, t, __builtin_elementwise_max(y, Z2));
}
__device__ __forceinline__ void sp100_4(f32x4& v) {
    f32x2 y0 = {v[0], v[1]}, y1 = {v[2], v[3]};
    f32x2 r0 = sp100_pair(y0), r1 = sp100_pair(y1);
    v[0] = r0.x; v[1] = r0.y; v[2] = r1.x; v[3] = r1.y;
}

// LDS tile [64 rows][256 cols] bf16, row stride 512B.
// byte ^= ((row&7) ^ 5*bit3(row)) << 4 — bijective, keeps 8/16B alignment.
__device__ __forceinline__ int xswz(int row) {
    return (((row & 7) ^ (5 * ((row >> 3) & 1))) << 4);
}
__device__ __forceinline__ short* xaddr(short* base, int row, int col) {
    int off = ((row << 9) + (col << 1)) ^ xswz(row);
    return (short*)((char*)base + off);
}
__device__ __forceinline__ const short* xaddrc(const short* base, int row, int col) {
    int off = ((row << 9) + (col << 1)) ^ xswz(row);
    return (const short*)((const char*)base + off);
}

// ---------------- weight prep: f32 row-major -> bf16 fragment-major (R7 verbatim) --
__global__ void prep_kernel(
    const float* __restrict__ W0, const float* __restrict__ W1, const float* __restrict__ W2,
    const float* __restrict__ W3, const float* __restrict__ W4, const float* __restrict__ W5,
    const float* __restrict__ W6, const float* __restrict__ W7, const float* __restrict__ W8,
    short* __restrict__ wbf)
{
    const int gid = blockIdx.x * blockDim.x + threadIdx.x;
    if (gid >= 68096) return;                       // total 16B chunks
    int l, cid; const float* Wsrc;
    if      (gid <  2048) { l = 0; cid = gid;         Wsrc = W0; }
    else if (gid < 10240) { l = 1; cid = gid -  2048; Wsrc = W1; }
    else if (gid < 18432) { l = 2; cid = gid - 10240; Wsrc = W2; }
    else if (gid < 26624) { l = 3; cid = gid - 18432; Wsrc = W3; }
    else if (gid < 34816) { l = 4; cid = gid - 26624; Wsrc = W4; }
    else if (gid < 43008) { l = 5; cid = gid - 34816; Wsrc = W5; }
    else if (gid < 51200) { l = 6; cid = gid - 43008; Wsrc = W6; }
    else if (gid < 59392) { l = 7; cid = gid - 51200; Wsrc = W7; }
    else                  { l = 8; cid = gid - 59392; Wsrc = W8; }
    const int NR   = (l == 3) ? 253 : ((l == 8) ? 257 : 256);
    const int KR   = (l == 0) ? 51 : 256;
    const int klog = (l == 0) ? 1 : 3;              // ktiles = Kpad/32 = 2 or 8
    const float sc = (l == 4) ? 0.70710678f : 1.0f; // fold skip 1/sqrt2 into W4
    const int lane  = cid & 63;
    const int tile  = cid >> 6;
    const int ntile = tile >> klog;
    const int ktile = tile & ((1 << klog) - 1);
    const int n  = ntile * 16 + (lane & 15);
    const int k0 = ktile * 32 + ((lane >> 4) << 3);
    bf16x8 v;
#pragma unroll
    for (int j = 0; j < 8; ++j) {
        int k = k0 + j;
        float f = (n < NR && k < KR) ? Wsrc[n * KR + k] * sc : 0.0f;
        v[j] = f2bf(f);
    }
    ((bf16x8*)wbf)[gid] = v;
}

// ------- one hidden layer, PING-PONG, a & b double-buffered (R10 body) ------------
// ap in: ks=0 A-frags of THIS layer. ap out: ks=0 frags of NEXT layer.
// bp in: bias frags of THIS layer (prefetched). bp out: bias of NEXT layer.
// MODE: 1 for layer 3 (N=253, masked col block 252). MODE_NEXT: next layer's MODE
// (controls bias-prefetch masking so we never read past b3[252]).
template<int KSTEPS, int MODE, int MODE_NEXT>
__device__ __forceinline__ void layer_fwd(const short* src, short* dst,
    const bf16x8* __restrict__ wl, const bf16x8* __restrict__ wlnext,
    const float* __restrict__ bias_next, int lane, int wid,
    bf16x8 (&ap)[4], f32x4 (&bp)[4])
{
    const int prow = lane & 15;
    const int kg   = (lane >> 4) << 3;
    const int rb4  = (lane >> 4) << 2;
    // bias (prefetched last layer) folded into accumulator init
    f32x4 acc[4][4];
#pragma unroll
    for (int nii = 0; nii < 4; ++nii)
#pragma unroll
        for (int mi = 0; mi < 4; ++mi)
            acc[mi][nii] = bp[nii];
    bf16x8 a_cur[4], b_cur[4];
#pragma unroll
    for (int nii = 0; nii < 4; ++nii) a_cur[nii] = ap[nii];
#pragma unroll
    for (int mi = 0; mi < 4; ++mi)
        b_cur[mi] = *(const bf16x8*)xaddrc(src, mi * 16 + prow, kg);
#pragma unroll
    for (int ks = 0; ks < KSTEPS; ++ks) {
        bf16x8 a_nxt[4], b_nxt[4];
        if (ks + 1 < KSTEPS) {
#pragma unroll
            for (int nii = 0; nii < 4; ++nii)
                a_nxt[nii] = wl[((wid * 4 + nii) * KSTEPS + ks + 1) * 64 + lane];
#pragma unroll
            for (int mi = 0; mi < 4; ++mi)
                b_nxt[mi] = *(const bf16x8*)xaddrc(src, mi * 16 + prow,
                                                   (ks + 1) * 32 + kg);
        } else {
#pragma unroll
            for (int nii = 0; nii < 4; ++nii)
                a_nxt[nii] = wlnext[(wid * 4 + nii) * 512 + lane];  // next layer ks=0
        }
        __builtin_amdgcn_s_setprio(1);
#pragma unroll
        for (int mi = 0; mi < 4; ++mi)
#pragma unroll
            for (int nii = 0; nii < 4; ++nii)
                acc[mi][nii] = __builtin_amdgcn_mfma_f32_16x16x32_bf16(
                    a_cur[nii], b_cur[mi], acc[mi][nii], 0, 0, 0);
        __builtin_amdgcn_s_setprio(0);
#pragma unroll
        for (int nii = 0; nii < 4; ++nii) a_cur[nii] = a_nxt[nii];
        if (ks + 1 < KSTEPS) {
#pragma unroll
            for (int mi = 0; mi < 4; ++mi) b_cur[mi] = b_nxt[mi];
        }
    }
#pragma unroll
    for (int nii = 0; nii < 4; ++nii) ap[nii] = a_cur[nii];
    // prefetch next layer's bias frags (ride through softplus+write+barrier)
#pragma unroll
    for (int nii = 0; nii < 4; ++nii) {
        const int cb = (wid * 4 + nii) * 16 + rb4;
        if (MODE_NEXT == 1 && cb == 252) {
            f32x4 tb = {bias_next[252], 0.f, 0.f, 0.f}; bp[nii] = tb;
        } else {
            bp[nii] = *(const f32x4*)(bias_next + cb);
        }
    }
    // softplus in place on acc (registers only)
#pragma unroll
    for (int nii = 0; nii < 4; ++nii)
#pragma unroll
        for (int mi = 0; mi < 4; ++mi)
            sp100_4(acc[mi][nii]);
    // write straight to dst (ping-pong: different buffer, no read barrier needed)
#pragma unroll
    for (int nii = 0; nii < 4; ++nii) {
        const int cb = (wid * 4 + nii) * 16 + rb4;
#pragma unroll
        for (int mi = 0; mi < 4; ++mi) {
            unsigned p01 = cvt_pk_bf16(acc[mi][nii][0], acc[mi][nii][1]);
            unsigned p23 = cvt_pk_bf16(acc[mi][nii][2], acc[mi][nii][3]);
            if (MODE == 1 && cb == 252) {
                *xaddr(dst, mi * 16 + prow, 252) = (short)(p01 & 0xffff);
            } else {
                uint2 pk; pk.x = p01; pk.y = p23;
                *(uint2*)xaddr(dst, mi * 16 + prow, cb) = pk;
            }
        }
    }
}

// ---------------- fused network kernel: 64 points, 4 waves, 2x32 KB LDS ------------
__global__ __launch_bounds__(256, 2) void net_kernel(
    const float* __restrict__ xin, const float* __restrict__ cond,
    const bf16x8* __restrict__ W,
    const float* __restrict__ b0, const float* __restrict__ b1, const float* __restrict__ b2,
    const float* __restrict__ b3, const float* __restrict__ b4, const float* __restrict__ b5,
    const float* __restrict__ b6, const float* __restrict__ b7, const float* __restrict__ b8,
    float* __restrict__ out)
{
    __shared__ short xb0[64 * 256];
    __shared__ short xb1[64 * 256];
    const int t    = threadIdx.x;
    const int pt0  = blockIdx.x * 64;
    const int lane = t & 63;
    const int wid  = t >> 6;      // 0..3
    const int rb4  = (lane >> 4) << 2;

    // prefetch L0 ks=0 A-frags + L0 bias first (hide under X0 build)
    bf16x8 ap[4];
    f32x4  bp[4];
#pragma unroll
    for (int nii = 0; nii < 4; ++nii) {
        ap[nii] = W[(wid * 4 + nii) * 128 + lane];   // KSTEPS(L0)=2
        bp[nii] = *(const f32x4*)(b0 + (wid * 4 + nii) * 16 + rb4);
    }

    // hoist skip values (written alongside layer 3; 1/sqrt2 folded into W4)
    float sk[3] = {0.f, 0.f, 0.f};
    if (t < 64) {
#pragma unroll
        for (int c = 0; c < 3; ++c)
            sk[c] = xin[(pt0 + t) * 3 + c];
    }

    // build X0 = [x(3) | cond(48) | zeros(..63)], bf16 into xb0 cols 0..63
    {
        const int row   = t >> 2;           // 0..63
        const int c0    = (t & 3) << 4;     // 0,16,32,48
        const int point = pt0 + row;
        const int batch = point / PPTS;
        const float* xp = xin + point * 3;
        const float* cp = cond + batch * 48;
#pragma unroll
        for (int h = 0; h < 2; ++h) {
            bf16x8 v;
#pragma unroll
            for (int i = 0; i < 8; ++i) {
                int c = c0 + h * 8 + i;
                float f = (c < 3) ? xp[c] : ((c < 51) ? cp[c - 3] : 0.0f);
                v[i] = f2bf(f);
            }
            *(bf16x8*)xaddr(xb0, row, c0 + h * 8) = v;
        }
    }
    bar_lgkm();

    layer_fwd<2, 0, 0>(xb0, xb1, W +     0, W +  2048, b1, lane, wid, ap, bp); bar_lgkm();
    layer_fwd<8, 0, 0>(xb1, xb0, W +  2048, W + 10240, b2, lane, wid, ap, bp); bar_lgkm();
    layer_fwd<8, 0, 1>(xb0, xb1, W + 10240, W + 18432, b3, lane, wid, ap, bp); bar_lgkm();
    // L3 (xb1 -> xb0); skip-concat writes xb0 cols 253..255 in the same window
    if (t < 64) {
#pragma unroll
        for (int c = 0; c < 3; ++c)
            *xaddr(xb0, t, 253 + c) = f2bf(sk[c]);
    }
    layer_fwd<8, 1, 0>(xb1, xb0, W + 18432, W + 26624, b4, lane, wid, ap, bp); bar_lgkm();
    layer_fwd<8, 0, 0>(xb0, xb1, W + 26624, W + 34816, b5, lane, wid, ap, bp); bar_lgkm();
    layer_fwd<8, 0, 0>(xb1, xb0, W + 34816, W + 43008, b6, lane, wid, ap, bp); bar_lgkm();
    layer_fwd<8, 0, 0>(xb0, xb1, W + 43008, W + 51200, b7, lane, wid, ap, bp); bar_lgkm();
    layer_fwd<8, 0, 0>(xb1, xb0, W + 51200, W + 59392, b8, lane, wid, ap, bp); bar_lgkm();

    // layer 8: reads xb0; N=257 (17 n-tiles), no activation, f32 store.
    // Two m-halves (live acc small); ap feeds half 0 ks 0; bias = prefetched bp.
    {
        const bf16x8* wl = W + 59392;
        const int prow = lane & 15;
        const int kg   = (lane >> 4) << 3;
        const float blast = b8[256];
#pragma unroll
        for (int half = 0; half < 2; ++half) {
            f32x4 acc[2][4];
            f32x4 acc2[2];
#pragma unroll
            for (int nii = 0; nii < 4; ++nii) {
#pragma unroll
                for (int m2 = 0; m2 < 2; ++m2)
                    acc[m2][nii] = bp[nii];
            }
            {
                f32x4 bz = {(rb4 == 0) ? blast : 0.f, 0.f, 0.f, 0.f};
                acc2[0] = bz; acc2[1] = bz;
            }
            bf16x8 a_cur[4];
#pragma unroll
            for (int nii = 0; nii < 4; ++nii)
                a_cur[nii] = (half == 0) ? ap[nii]
                           : wl[((wid * 4 + nii) * 8) * 64 + lane];
#pragma unroll
            for (int ks = 0; ks < 8; ++ks) {
                bf16x8 a_nxt[4], a2;
                if (ks < 7) {
#pragma unroll
                    for (int nii = 0; nii < 4; ++nii)
                        a_nxt[nii] = wl[((wid * 4 + nii) * 8 + ks + 1) * 64 + lane];
                }
                if (wid == 0) a2 = wl[(128 + ks) * 64 + lane];
                bf16x8 b[2];
#pragma unroll
                for (int m2 = 0; m2 < 2; ++m2)
                    b[m2] = *(const bf16x8*)xaddrc(xb0, (half * 2 + m2) * 16 + prow,
                                                   ks * 32 + kg);
                __builtin_amdgcn_s_setprio(1);
#pragma unroll
                for (int m2 = 0; m2 < 2; ++m2)
#pragma unroll
                    for (int nii = 0; nii < 4; ++nii)
                        acc[m2][nii] = __builtin_amdgcn_mfma_f32_16x16x32_bf16(
                            a_cur[nii], b[m2], acc[m2][nii], 0, 0, 0);
                if (wid == 0) {
#pragma unroll
                    for (int m2 = 0; m2 < 2; ++m2)
                        acc2[m2] = __builtin_amdgcn_mfma_f32_16x16x32_bf16(
                            a2, b[m2], acc2[m2], 0, 0, 0);
                }
                __builtin_amdgcn_s_setprio(0);
                if (ks < 7) {
#pragma unroll
                    for (int nii = 0; nii < 4; ++nii) a_cur[nii] = a_nxt[nii];
                }
            }
#pragma unroll
            for (int nii = 0; nii < 4; ++nii) {
                const int cb = (wid * 4 + nii) * 16 + rb4;          // <= 252
#pragma unroll
                for (int m2 = 0; m2 < 2; ++m2) {
                    const int rowoff = (pt0 + (half * 2 + m2) * 16 + prow) * 257 + cb;
#pragma unroll
                    for (int r = 0; r < 4; ++r)
                        out[rowoff + r] = acc[m2][nii][r];
                }
            }
            if (wid == 0 && rb4 == 0) {                              // lanes 0..15
#pragma unroll
                for (int m2 = 0; m2 < 2; ++m2)
                    out[(pt0 + (half * 2 + m2) * 16 + prow) * 257 + 256]
                        = acc2[m2][0];
            }
        }
    }
}

extern "C" void kernel_launch(void* const* d_in, const int* in_sizes, int n_in,
                              void* d_out, int out_size, void* d_ws, size_t ws_size,
                              hipStream_t stream)
{
    const float* xin  = (const float*)d_in[0];
    const float* cond = (const float*)d_in[1];
    const float* Wp[9]; const float* bp[9];
    for (int l = 0; l < 9; ++l) { Wp[l] = (const float*)d_in[2 + 2 * l]; bp[l] = (const float*)d_in[3 + 2 * l]; }
    short* wbf = (short*)d_ws;   // needs 1,089,536 B

    prep_kernel<<<dim3(266), dim3(256), 0, stream>>>(
        Wp[0], Wp[1], Wp[2], Wp[3], Wp[4], Wp[5], Wp[6], Wp[7], Wp[8], wbf);
    net_kernel<<<dim3(3125), dim3(256), 0, stream>>>(
        xin, cond, (const bf16x8*)wbf,
        bp[0], bp[1], bp[2], bp[3], bp[4], bp[5], bp[6], bp[7], bp[8],
        (float*)d_out);
}